// Round 2
// baseline (2605.390 us; speedup 1.0000x reference)
//
#include <hip/hip_runtime.h>
#include <hip/hip_bf16.h>

// Net_4544075399853: per-timestep scalar->20 linear, LSTMCell(20,20), 20->1 linear.
// B=8192 independent rows, T=2048 sequential steps. ALL fp32 (reference dtypes).
// Layout (R2):
//  - thread = (row, hidden_unit): 20 threads/row; block = 16 rows = 320 threads.
//  - W_hh slice (4 gates x 20 = 80 coeffs) lives in VGPRs, loaded once.
//  - linear1 folded: gates[j] = x*u[j] + v[j] + W_hh[j,:]@h, u=W_ih@W1, v=W_ih@b1+b_ih+b_hh.
//  - h shared through double-buffered LDS; ONE __syncthreads per step.
//  - x[t+1] prefetched one step ahead to hide global-load latency.

#define HID 20
#define ROWS_PER_BLOCK 16
#define NTHREADS (ROWS_PER_BLOCK * HID)   // 320 threads = 5 waves

__device__ __forceinline__ float fast_sigmoid(float v) {
    return __builtin_amdgcn_rcpf(1.0f + __expf(-v));
}
__device__ __forceinline__ float fast_tanh(float v) {
    // tanh(v) = 1 - 2/(exp(2v)+1); saturates correctly at +-inf.
    return 1.0f - 2.0f * __builtin_amdgcn_rcpf(1.0f + __expf(2.0f * v));
}

__global__ __launch_bounds__(NTHREADS) void lstm_fused(
        const float* __restrict__ x,     // [B, T]
        const float* __restrict__ W1,    // [20]
        const float* __restrict__ b1,    // [20]
        const float* __restrict__ W_ih,  // [80, 20]
        const float* __restrict__ W_hh,  // [80, 20]
        const float* __restrict__ b_ih,  // [80]
        const float* __restrict__ b_hh,  // [80]
        const float* __restrict__ W2,    // [20]
        const float* __restrict__ b2,    // [1]
        float* __restrict__ out,         // [B, T]
        const int T)
{
    const int tid  = threadIdx.x;
    const int lrow = tid / HID;   // local row 0..15
    const int m    = tid % HID;   // hidden unit 0..19
    const long row = (long)blockIdx.x * ROWS_PER_BLOCK + lrow;

    __shared__ __align__(16) float hbuf[2][ROWS_PER_BLOCK][HID];

    // ---- one-time weight preload into registers ----
    float w1r[HID], b1r[HID], w2r[HID];
#pragma unroll
    for (int k = 0; k < HID; ++k) {
        w1r[k] = W1[k];
        b1r[k] = b1[k];
        w2r[k] = W2[k];
    }

    float whh[4][HID];   // my 4 gate rows of W_hh
    float u[4], v[4];
#pragma unroll
    for (int g = 0; g < 4; ++g) {
        const int j = g * HID + m;            // torch gate order i,f,g,o
        float uu = 0.f, vv = 0.f;
#pragma unroll
        for (int k = 0; k < HID; ++k) {
            whh[g][k] = W_hh[j * HID + k];
            const float wi = W_ih[j * HID + k];
            uu += wi * w1r[k];
            vv += wi * b1r[k];
        }
        u[g] = uu;
        v[g] = vv + b_ih[j] + b_hh[j];
    }
    const float b2v = b2[0];

    // ---- state init ----
    float c = 0.f;
    hbuf[0][lrow][m] = 0.f;
    __syncthreads();

    const float* __restrict__ xrow = x   + row * T;
    float* __restrict__       orow = out + row * T;

    float xv_next = xrow[0];

    for (int t = 0; t < T; ++t) {
        const float xv = xv_next;
        xv_next = (t + 1 < T) ? xrow[t + 1] : 0.f;   // prefetch next step's x

        // h_prev for my row (h_new of step t-1), vectorized LDS read
        float h[HID];
        const float4* hp = (const float4*)hbuf[t & 1][lrow];
#pragma unroll
        for (int q = 0; q < 5; ++q) {
            const float4 f = hp[q];
            h[4*q+0] = f.x; h[4*q+1] = f.y; h[4*q+2] = f.z; h[4*q+3] = f.w;
        }

        // out[t-1] = W2 @ h_prev + b2 (h here IS h_new of t-1)
        if (t > 0 && m == 0) {
            float o = b2v;
#pragma unroll
            for (int k = 0; k < HID; ++k) o += h[k] * w2r[k];
            orow[t - 1] = o;
        }

        float g0 = v[0] + xv * u[0];
        float g1 = v[1] + xv * u[1];
        float g2 = v[2] + xv * u[2];
        float g3 = v[3] + xv * u[3];
#pragma unroll
        for (int k = 0; k < HID; ++k) {
            g0 += whh[0][k] * h[k];
            g1 += whh[1][k] * h[k];
            g2 += whh[2][k] * h[k];
            g3 += whh[3][k] * h[k];
        }

        const float ig = fast_sigmoid(g0);
        const float fg = fast_sigmoid(g1);
        const float gg = fast_tanh(g2);
        const float og = fast_sigmoid(g3);
        c = fg * c + ig * gg;
        const float hn = og * fast_tanh(c);

        hbuf[(t + 1) & 1][lrow][m] = hn;
        __syncthreads();
    }

    // final output: out[T-1] from the last h (in buf[T&1], barrier already passed)
    if (m == 0) {
        float o = b2v;
        const float* hf = hbuf[T & 1][lrow];
#pragma unroll
        for (int k = 0; k < HID; ++k) o += hf[k] * w2r[k];
        orow[T - 1] = o;
    }
}

extern "C" void kernel_launch(void* const* d_in, const int* in_sizes, int n_in,
                              void* d_out, int out_size, void* d_ws, size_t ws_size,
                              hipStream_t stream) {
    (void)n_in; (void)d_ws; (void)ws_size; (void)out_size;
    const float* x    = (const float*)d_in[0];
    const float* W1   = (const float*)d_in[1];
    const float* b1   = (const float*)d_in[2];
    const float* W_ih = (const float*)d_in[3];
    const float* W_hh = (const float*)d_in[4];
    const float* b_ih = (const float*)d_in[5];
    const float* b_hh = (const float*)d_in[6];
    const float* W2   = (const float*)d_in[7];
    const float* b2   = (const float*)d_in[8];
    float* out        = (float*)d_out;

    const int B = 8192;
    const int T = in_sizes[0] / B;       // 2048
    const int grid = B / ROWS_PER_BLOCK; // 512 blocks

    lstm_fused<<<grid, NTHREADS, 0, stream>>>(x, W1, b1, W_ih, W_hh, b_ih, b_hh, W2, b2, out, T);
}

// Round 3
// 1835.262 us; speedup vs baseline: 1.4196x; 1.4196x over previous
//
#include <hip/hip_runtime.h>
#include <hip/hip_bf16.h>

// Net_4544075399853: per-timestep scalar->20 linear, LSTMCell(20,20), 20->1 linear.
// B=8192 independent rows, T=2048 sequential steps. ALL fp32.
// R3: single-wave workgroups. 1 wave = 3 rows x 20 hidden units (lanes 60-63 idle).
//  - No inter-wave barriers ever: __syncthreads on a 1-wave block is immediate.
//  - 2731 blocks ~ 10.7 single-wave workgroups/CU -> waves stall independently,
//    latency hidden by co-resident waves instead of blocking sibling waves.
//  - W_hh slice (4 gates x 20) in VGPRs; linear1 folded: u=W_ih@W1, v=W_ih@b1+b_ih+b_hh.
//  - h exchanged through tiny double-buffered LDS (640 B/block).

#define HID 20
#define ROWS_PER_WAVE 3
#define NTHREADS 64

__device__ __forceinline__ float fast_sigmoid(float v) {
    return __builtin_amdgcn_rcpf(1.0f + __expf(-v));
}
__device__ __forceinline__ float fast_tanh(float v) {
    // tanh(v) = 1 - 2/(exp(2v)+1); saturates correctly at +-inf.
    return 1.0f - 2.0f * __builtin_amdgcn_rcpf(1.0f + __expf(2.0f * v));
}

__global__ __launch_bounds__(NTHREADS) void lstm_wave(
        const float* __restrict__ x,     // [B, T]
        const float* __restrict__ W1,    // [20]
        const float* __restrict__ b1,    // [20]
        const float* __restrict__ W_ih,  // [80, 20]
        const float* __restrict__ W_hh,  // [80, 20]
        const float* __restrict__ b_ih,  // [80]
        const float* __restrict__ b_hh,  // [80]
        const float* __restrict__ W2,    // [20]
        const float* __restrict__ b2,    // [1]
        float* __restrict__ out,         // [B, T]
        const int B, const int T)
{
    const int lane = threadIdx.x;
    const int lrow = lane / HID;          // 0..2 active, 3 = idle lanes 60-63
    const int m    = lane % HID;          // hidden unit
    const long row  = (long)blockIdx.x * ROWS_PER_WAVE + lrow;
    const bool rowvalid = (lrow < ROWS_PER_WAVE) && (row < B);
    const long arow = rowvalid ? row : 0;  // safe address for inactive lanes

    // [2 buffers][4 row slots (slot 3 = trash for idle lanes)][20 units]
    __shared__ __align__(16) float hbuf[2][ROWS_PER_WAVE + 1][HID];

    // ---- one-time weight preload into registers ----
    float w1r[HID], b1r[HID], w2r[HID];
#pragma unroll
    for (int k = 0; k < HID; ++k) {
        w1r[k] = W1[k];
        b1r[k] = b1[k];
        w2r[k] = W2[k];
    }

    float whh[4][HID];   // my 4 gate rows of W_hh (torch order i,f,g,o)
    float u[4], v[4];
#pragma unroll
    for (int g = 0; g < 4; ++g) {
        const int j = g * HID + m;
        float uu = 0.f, vv = 0.f;
#pragma unroll
        for (int k = 0; k < HID; ++k) {
            whh[g][k] = W_hh[j * HID + k];
            const float wi = W_ih[j * HID + k];
            uu += wi * w1r[k];
            vv += wi * b1r[k];
        }
        u[g] = uu;
        v[g] = vv + b_ih[j] + b_hh[j];
    }
    const float b2v = b2[0];

    // ---- state init ----
    float c = 0.f;
    hbuf[0][lrow][m] = 0.f;
    __syncthreads();   // single-wave: just an LDS drain, effectively free

    const float* __restrict__ xrow = x   + arow * T;
    float* __restrict__       orow = out + arow * T;

    float xv_next = xrow[0];

    for (int t = 0; t < T; ++t) {
        const float xv = xv_next;
        const int tn = (t + 1 < T) ? (t + 1) : (T - 1);  // uniform clamp, no cndmask
        xv_next = xrow[tn];

        // h_prev for my row (h_new of step t-1), vectorized LDS read (broadcast
        // within each 20-lane row group -> conflict-free)
        float h[HID];
        const float4* hp = (const float4*)hbuf[t & 1][lrow];
#pragma unroll
        for (int q = 0; q < 5; ++q) {
            const float4 f = hp[q];
            h[4*q+0] = f.x; h[4*q+1] = f.y; h[4*q+2] = f.z; h[4*q+3] = f.w;
        }

        // out[t-1] = W2 @ h_prev + b2 (h IS h_new of step t-1)
        if (t > 0 && m == 0 && rowvalid) {
            float o = b2v;
#pragma unroll
            for (int k = 0; k < HID; ++k) o += h[k] * w2r[k];
            orow[t - 1] = o;
        }

        float g0 = v[0] + xv * u[0];
        float g1 = v[1] + xv * u[1];
        float g2 = v[2] + xv * u[2];
        float g3 = v[3] + xv * u[3];
#pragma unroll
        for (int k = 0; k < HID; ++k) {
            g0 += whh[0][k] * h[k];
            g1 += whh[1][k] * h[k];
            g2 += whh[2][k] * h[k];
            g3 += whh[3][k] * h[k];
        }

        const float ig = fast_sigmoid(g0);
        const float fg = fast_sigmoid(g1);
        const float gg = fast_tanh(g2);
        const float og = fast_sigmoid(g3);
        c = fg * c + ig * gg;
        const float hn = og * fast_tanh(c);

        hbuf[(t + 1) & 1][lrow][m] = hn;
        __syncthreads();   // 1-wave barrier: orders LDS within the wave, no stall
    }

    // final output: out[T-1] from the last h
    if (m == 0 && rowvalid) {
        float o = b2v;
        const float* hf = hbuf[T & 1][lrow];
#pragma unroll
        for (int k = 0; k < HID; ++k) o += hf[k] * w2r[k];
        orow[T - 1] = o;
    }
}

extern "C" void kernel_launch(void* const* d_in, const int* in_sizes, int n_in,
                              void* d_out, int out_size, void* d_ws, size_t ws_size,
                              hipStream_t stream) {
    (void)n_in; (void)d_ws; (void)ws_size; (void)out_size;
    const float* x    = (const float*)d_in[0];
    const float* W1   = (const float*)d_in[1];
    const float* b1   = (const float*)d_in[2];
    const float* W_ih = (const float*)d_in[3];
    const float* W_hh = (const float*)d_in[4];
    const float* b_ih = (const float*)d_in[5];
    const float* b_hh = (const float*)d_in[6];
    const float* W2   = (const float*)d_in[7];
    const float* b2   = (const float*)d_in[8];
    float* out        = (float*)d_out;

    const int B = 8192;
    const int T = in_sizes[0] / B;  // 2048
    const int grid = (B + ROWS_PER_WAVE - 1) / ROWS_PER_WAVE;  // 2731 single-wave blocks

    lstm_wave<<<grid, NTHREADS, 0, stream>>>(x, W1, b1, W_ih, W_hh, b_ih, b_hh, W2, b2, out, B, T);
}

// Round 4
// 1312.924 us; speedup vs baseline: 1.9844x; 1.3978x over previous
//
#include <hip/hip_runtime.h>

// Net_4544075399853: x->20 linear, LSTMCell(20,20), 20->1 linear; B=8192, T=2048, fp32.
// R4: spill-free single-wave kernel.
//  - __launch_bounds__(64,4): VGPR cap 128. R3's (64) alone squeezed to 64 VGPRs and
//    spilled the 80-entry whh array -> ~80 reloads/step (the 2x gap vs issue model).
//  - Lanes 0-59: 3 rows x 20 units, whh[4][20] resident in VGPRs.
//  - Lanes 60-62: "output lanes" — whh[0]=W2, v[0]=b2, u=0, read row r's h -> their
//    g0 IS out[t-1]. Output dot costs zero extra instructions.
//  - h streamed as float4 from 640B double-buffered LDS; manual unroll x2 kills the
//    t&1 address selects. One trivial single-wave __syncthreads per step.

#define HID 20
#define ROWS_PER_WAVE 3
#define NTHREADS 64

__device__ __forceinline__ float fast_sigmoid(float v) {
    return __builtin_amdgcn_rcpf(1.0f + __expf(-v));
}
__device__ __forceinline__ float fast_tanh(float v) {
    // tanh(v) = 1 - 2/(exp(2v)+1); saturates correctly at +-inf.
    return 1.0f - 2.0f * __builtin_amdgcn_rcpf(1.0f + __expf(2.0f * v));
}

__global__ __launch_bounds__(NTHREADS, 4) void lstm_wave(
        const float* __restrict__ x,     // [B, T]
        const float* __restrict__ W1,    // [20]
        const float* __restrict__ b1,    // [20]
        const float* __restrict__ W_ih,  // [80, 20]
        const float* __restrict__ W_hh,  // [80, 20]
        const float* __restrict__ b_ih,  // [80]
        const float* __restrict__ b_hh,  // [80]
        const float* __restrict__ W2,    // [20]
        const float* __restrict__ b2,    // [1]
        float* __restrict__ out,         // [B, T]
        const int B, const int T)
{
    const int lane = threadIdx.x;
    const int lrow = lane / HID;          // 0..3 (3 = special lanes 60-63)
    const int m    = lane % HID;          // 0..19
    const bool outlane = (lrow == 3) && (m < ROWS_PER_WAVE);   // lanes 60,61,62
    const int rslot = (lrow == 3) ? m : lrow;  // LDS row slot this lane READS (lane63 -> trash slot 3)
    const long rowbase = (long)blockIdx.x * ROWS_PER_WAVE;
    const long row = rowbase + ((lrow == 3) ? (long)((m < 3) ? m : 0) : (long)lrow);
    const long arow = (row < B) ? row : (B - 1);     // safe address for OOB/aux lanes
    const bool ovalid = outlane && (row < B);

    // [2 buffers][4 row slots (slot 3 = trash)][20 units]; row stride 80B (16B aligned)
    __shared__ __align__(16) float hbuf[2][ROWS_PER_WAVE + 1][HID];

    float whh[4][HID];   // gate lanes: my 4 W_hh rows. out lanes: whh[0]=W2, rest 0.
    float u[4], v[4];

    if (lrow < 3) {
        float w1r[HID], b1r[HID];
#pragma unroll
        for (int k = 0; k < HID; ++k) { w1r[k] = W1[k]; b1r[k] = b1[k]; }
#pragma unroll
        for (int g = 0; g < 4; ++g) {
            const int j = g * HID + m;            // torch gate order i,f,g,o
            float uu = 0.f, vv = 0.f;
#pragma unroll
            for (int k = 0; k < HID; ++k) {
                whh[g][k] = W_hh[j * HID + k];
                const float wi = W_ih[j * HID + k];
                uu += wi * w1r[k];
                vv += wi * b1r[k];
            }
            u[g] = uu;
            v[g] = vv + b_ih[j] + b_hh[j];
        }
    } else {
        // output lanes: gate-0 dot computes b2 + W2 @ h
#pragma unroll
        for (int g = 0; g < 4; ++g) { u[g] = 0.f; v[g] = 0.f; }
#pragma unroll
        for (int k = 0; k < HID; ++k) {
            whh[0][k] = W2[k];
            whh[1][k] = 0.f; whh[2][k] = 0.f; whh[3][k] = 0.f;
        }
        v[0] = b2[0];
    }

    float c = 0.f;
    hbuf[0][lrow][m] = 0.f;
    hbuf[1][lrow][m] = 0.f;
    __syncthreads();

    const float* __restrict__ xrow = x   + arow * T;
    float* __restrict__       orow = out + arow * T;

    const float4* __restrict__ rd0 = (const float4*)&hbuf[0][rslot][0];
    const float4* __restrict__ rd1 = (const float4*)&hbuf[1][rslot][0];
    float* __restrict__ wr0 = &hbuf[1][lrow][m];   // body A writes buf1
    float* __restrict__ wr1 = &hbuf[0][lrow][m];   // body B writes buf0

    float xv_next = xrow[0];

    for (int t = 0; t < T; t += 2) {
        // ---- body A: h_t in buf0 -> h_{t+1} in buf1 ----
        {
            const float xv = xv_next;
            xv_next = xrow[t + 1];                 // t+1 <= T-1 always (T even)
            float g0 = v[0] + xv * u[0];
            float g1 = v[1] + xv * u[1];
            float g2 = v[2] + xv * u[2];
            float g3 = v[3] + xv * u[3];
#pragma unroll
            for (int q = 0; q < 5; ++q) {
                const float4 f = rd0[q];
                const float hk[4] = {f.x, f.y, f.z, f.w};
#pragma unroll
                for (int r = 0; r < 4; ++r) {
                    const int k = 4 * q + r;
                    g0 += whh[0][k] * hk[r];
                    g1 += whh[1][k] * hk[r];
                    g2 += whh[2][k] * hk[r];
                    g3 += whh[3][k] * hk[r];
                }
            }
            if (t > 0 && ovalid) orow[t - 1] = g0;   // out lanes: g0 = b2 + W2@h_t

            const float ig = fast_sigmoid(g0);
            const float fg = fast_sigmoid(g1);
            const float gg = fast_tanh(g2);
            const float og = fast_sigmoid(g3);
            c = fg * c + ig * gg;
            *wr0 = og * fast_tanh(c);
            __syncthreads();   // single-wave: lgkm drain only
        }
        // ---- body B: h_{t+1} in buf1 -> h_{t+2} in buf0 ----
        {
            const float xv = xv_next;
            const int tn = (t + 2 < T) ? (t + 2) : (T - 1);
            xv_next = xrow[tn];
            float g0 = v[0] + xv * u[0];
            float g1 = v[1] + xv * u[1];
            float g2 = v[2] + xv * u[2];
            float g3 = v[3] + xv * u[3];
#pragma unroll
            for (int q = 0; q < 5; ++q) {
                const float4 f = rd1[q];
                const float hk[4] = {f.x, f.y, f.z, f.w};
#pragma unroll
                for (int r = 0; r < 4; ++r) {
                    const int k = 4 * q + r;
                    g0 += whh[0][k] * hk[r];
                    g1 += whh[1][k] * hk[r];
                    g2 += whh[2][k] * hk[r];
                    g3 += whh[3][k] * hk[r];
                }
            }
            if (ovalid) orow[t] = g0;                // out lanes: g0 = b2 + W2@h_{t+1}

            const float ig = fast_sigmoid(g0);
            const float fg = fast_sigmoid(g1);
            const float gg = fast_tanh(g2);
            const float og = fast_sigmoid(g3);
            c = fg * c + ig * gg;
            *wr1 = og * fast_tanh(c);
            __syncthreads();
        }
    }

    // epilogue: out[T-1] = b2 + W2 @ h_T ; h_T is in buf0 (T even)
    if (ovalid) {
        float o = v[0];
#pragma unroll
        for (int q = 0; q < 5; ++q) {
            const float4 f = rd0[q];
            o += whh[0][4*q+0] * f.x + whh[0][4*q+1] * f.y
               + whh[0][4*q+2] * f.z + whh[0][4*q+3] * f.w;
        }
        orow[T - 1] = o;
    }
}

extern "C" void kernel_launch(void* const* d_in, const int* in_sizes, int n_in,
                              void* d_out, int out_size, void* d_ws, size_t ws_size,
                              hipStream_t stream) {
    (void)n_in; (void)d_ws; (void)ws_size; (void)out_size;
    const float* x    = (const float*)d_in[0];
    const float* W1   = (const float*)d_in[1];
    const float* b1   = (const float*)d_in[2];
    const float* W_ih = (const float*)d_in[3];
    const float* W_hh = (const float*)d_in[4];
    const float* b_ih = (const float*)d_in[5];
    const float* b_hh = (const float*)d_in[6];
    const float* W2   = (const float*)d_in[7];
    const float* b2   = (const float*)d_in[8];
    float* out        = (float*)d_out;

    const int B = 8192;
    const int T = in_sizes[0] / B;  // 2048 (even)
    const int grid = (B + ROWS_PER_WAVE - 1) / ROWS_PER_WAVE;  // 2731 single-wave blocks

    lstm_wave<<<grid, NTHREADS, 0, stream>>>(x, W1, b1, W_ih, W_hh, b_ih, b_hh, W2, b2, out, B, T);
}

// Round 5
// 1289.587 us; speedup vs baseline: 2.0203x; 1.0181x over previous
//
#include <hip/hip_runtime.h>

// Net_4544075399853: x->20 linear, LSTMCell(20,20), 20->1 linear; B=8192, T=2048, fp32.
// R5: force W_hh register residency.
//  - R4 evidence: VGPR_Count stuck at 64 -> backend sank the 80 W_hh loads into the
//    loop (remat to hit 8-waves/SIMD occupancy that the grid can't even use).
//  - amdgpu_waves_per_eu(4,4): VGPR cap 128 AND no incentive to squeeze below
//    (grid only supplies ~2.67 waves/SIMD).
//  - asm volatile "+v" pin on each whh value: opaque def, cannot be rematerialized.
//  - Lanes 0-59: 3 rows x 20 units, whh[4][20] resident. Lanes 60-62: output lanes
//    (whh row0 = W2, v[0]=b2) -> their g0 IS out[t-1], zero extra dot cost.
//  - 640B double-buffered LDS h exchange, float4 reads, unroll x2, single-wave
//    workgroups (barrier is free).

#define HID 20
#define ROWS_PER_WAVE 3
#define NTHREADS 64

__device__ __forceinline__ float fast_sigmoid(float v) {
    return __builtin_amdgcn_rcpf(1.0f + __expf(-v));
}
__device__ __forceinline__ float fast_tanh(float v) {
    // tanh(v) = 1 - 2/(exp(2v)+1); saturates correctly at +-inf.
    return 1.0f - 2.0f * __builtin_amdgcn_rcpf(1.0f + __expf(2.0f * v));
}

__global__ __attribute__((amdgpu_flat_work_group_size(NTHREADS, NTHREADS),
                          amdgpu_waves_per_eu(4, 4)))
void lstm_wave(
        const float* __restrict__ x,     // [B, T]
        const float* __restrict__ W1,    // [20]
        const float* __restrict__ b1,    // [20]
        const float* __restrict__ W_ih,  // [80, 20]
        const float* __restrict__ W_hh,  // [80, 20]
        const float* __restrict__ b_ih,  // [80]
        const float* __restrict__ b_hh,  // [80]
        const float* __restrict__ W2,    // [20]
        const float* __restrict__ b2,    // [1]
        float* __restrict__ out,         // [B, T]
        const int B, const int T)
{
    const int lane = threadIdx.x;
    const int lrow = lane / HID;          // 0..3 (3 = special lanes 60-63)
    const int m    = lane % HID;          // 0..19
    const bool outlane = (lrow == 3) && (m < ROWS_PER_WAVE);   // lanes 60,61,62
    const int rslot = (lrow == 3) ? m : lrow;  // LDS row slot this lane READS
    const long rowbase = (long)blockIdx.x * ROWS_PER_WAVE;
    const long row = rowbase + ((lrow == 3) ? (long)((m < 3) ? m : 0) : (long)lrow);
    const long arow = (row < B) ? row : (B - 1);     // safe address for OOB/aux lanes
    const bool ovalid = outlane && (row < B);

    // [2 buffers][4 row slots (slot 3 = trash)][20 units]
    __shared__ __align__(16) float hbuf[2][ROWS_PER_WAVE + 1][HID];

    float whh[4][HID];   // gate lanes: my 4 W_hh rows. out lanes: whh[0]=W2, rest 0.
    float u[4], v[4];

    if (lrow < 3) {
        float w1r[HID], b1r[HID];
#pragma unroll
        for (int k = 0; k < HID; ++k) { w1r[k] = W1[k]; b1r[k] = b1[k]; }
#pragma unroll
        for (int g = 0; g < 4; ++g) {
            const int j = g * HID + m;            // torch gate order i,f,g,o
            float uu = 0.f, vv = 0.f;
#pragma unroll
            for (int k = 0; k < HID; ++k) {
                whh[g][k] = W_hh[j * HID + k];
                const float wi = W_ih[j * HID + k];
                uu += wi * w1r[k];
                vv += wi * b1r[k];
            }
            u[g] = uu;
            v[g] = vv + b_ih[j] + b_hh[j];
        }
    } else {
        // output lanes: gate-0 dot computes b2 + W2 @ h
#pragma unroll
        for (int g = 0; g < 4; ++g) { u[g] = 0.f; v[g] = 0.f; }
#pragma unroll
        for (int k = 0; k < HID; ++k) {
            whh[0][k] = W2[k];
            whh[1][k] = 0.f; whh[2][k] = 0.f; whh[3][k] = 0.f;
        }
        v[0] = b2[0];
    }

    // Opaque defs: the register allocator cannot rematerialize these loads into
    // the loop; with the (4,4) occupancy pin there is room to keep all 80 live.
#pragma unroll
    for (int g = 0; g < 4; ++g)
#pragma unroll
        for (int k = 0; k < HID; ++k)
            asm volatile("" : "+v"(whh[g][k]));

    float c = 0.f;
    hbuf[0][lrow][m] = 0.f;
    hbuf[1][lrow][m] = 0.f;
    __syncthreads();

    const float* __restrict__ xrow = x   + arow * T;
    float* __restrict__       orow = out + arow * T;

    const float4* __restrict__ rd0 = (const float4*)&hbuf[0][rslot][0];
    const float4* __restrict__ rd1 = (const float4*)&hbuf[1][rslot][0];
    float* __restrict__ wr0 = &hbuf[1][lrow][m];   // body A writes buf1
    float* __restrict__ wr1 = &hbuf[0][lrow][m];   // body B writes buf0

    float xv_next = xrow[0];

    for (int t = 0; t < T; t += 2) {
        // ---- body A: h_t in buf0 -> h_{t+1} in buf1 ----
        {
            const float xv = xv_next;
            xv_next = xrow[t + 1];                 // t+1 <= T-1 always (T even)
            float g0 = v[0] + xv * u[0];
            float g1 = v[1] + xv * u[1];
            float g2 = v[2] + xv * u[2];
            float g3 = v[3] + xv * u[3];
#pragma unroll
            for (int q = 0; q < 5; ++q) {
                const float4 f = rd0[q];
                const float hk[4] = {f.x, f.y, f.z, f.w};
#pragma unroll
                for (int r = 0; r < 4; ++r) {
                    const int k = 4 * q + r;
                    g0 += whh[0][k] * hk[r];
                    g1 += whh[1][k] * hk[r];
                    g2 += whh[2][k] * hk[r];
                    g3 += whh[3][k] * hk[r];
                }
            }
            if (t > 0 && ovalid) orow[t - 1] = g0;   // out lanes: g0 = b2 + W2@h_t

            const float ig = fast_sigmoid(g0);
            const float fg = fast_sigmoid(g1);
            const float gg = fast_tanh(g2);
            const float og = fast_sigmoid(g3);
            c = fg * c + ig * gg;
            *wr0 = og * fast_tanh(c);
            __syncthreads();   // single-wave: lgkm drain only
        }
        // ---- body B: h_{t+1} in buf1 -> h_{t+2} in buf0 ----
        {
            const float xv = xv_next;
            const int tn = (t + 2 < T) ? (t + 2) : (T - 1);
            xv_next = xrow[tn];
            float g0 = v[0] + xv * u[0];
            float g1 = v[1] + xv * u[1];
            float g2 = v[2] + xv * u[2];
            float g3 = v[3] + xv * u[3];
#pragma unroll
            for (int q = 0; q < 5; ++q) {
                const float4 f = rd1[q];
                const float hk[4] = {f.x, f.y, f.z, f.w};
#pragma unroll
                for (int r = 0; r < 4; ++r) {
                    const int k = 4 * q + r;
                    g0 += whh[0][k] * hk[r];
                    g1 += whh[1][k] * hk[r];
                    g2 += whh[2][k] * hk[r];
                    g3 += whh[3][k] * hk[r];
                }
            }
            if (ovalid) orow[t] = g0;                // out lanes: g0 = b2 + W2@h_{t+1}

            const float ig = fast_sigmoid(g0);
            const float fg = fast_sigmoid(g1);
            const float gg = fast_tanh(g2);
            const float og = fast_sigmoid(g3);
            c = fg * c + ig * gg;
            *wr1 = og * fast_tanh(c);
            __syncthreads();
        }
    }

    // epilogue: out[T-1] = b2 + W2 @ h_T ; h_T is in buf0 (T even)
    if (ovalid) {
        float o = v[0];
#pragma unroll
        for (int q = 0; q < 5; ++q) {
            const float4 f = rd0[q];
            o += whh[0][4*q+0] * f.x + whh[0][4*q+1] * f.y
               + whh[0][4*q+2] * f.z + whh[0][4*q+3] * f.w;
        }
        orow[T - 1] = o;
    }
}

extern "C" void kernel_launch(void* const* d_in, const int* in_sizes, int n_in,
                              void* d_out, int out_size, void* d_ws, size_t ws_size,
                              hipStream_t stream) {
    (void)n_in; (void)d_ws; (void)ws_size; (void)out_size;
    const float* x    = (const float*)d_in[0];
    const float* W1   = (const float*)d_in[1];
    const float* b1   = (const float*)d_in[2];
    const float* W_ih = (const float*)d_in[3];
    const float* W_hh = (const float*)d_in[4];
    const float* b_ih = (const float*)d_in[5];
    const float* b_hh = (const float*)d_in[6];
    const float* W2   = (const float*)d_in[7];
    const float* b2   = (const float*)d_in[8];
    float* out        = (float*)d_out;

    const int B = 8192;
    const int T = in_sizes[0] / B;  // 2048 (even)
    const int grid = (B + ROWS_PER_WAVE - 1) / ROWS_PER_WAVE;  // 2731 single-wave blocks

    lstm_wave<<<grid, NTHREADS, 0, stream>>>(x, W1, b1, W_ih, W_hh, b_ih, b_hh, W2, b2, out, B, T);
}

// Round 6
// 1226.885 us; speedup vs baseline: 2.1236x; 1.0511x over previous
//
#include <hip/hip_runtime.h>

// Net_4544075399853: x->20 linear, LSTMCell(20,20), 20->1 linear; B=8192, T=2048, fp32.
// R6: fix the self-inflicted AGPR spill.
//  - R5 evidence: VGPR_Count pinned at 64 with waves_per_eu(4,4) -> total-reg cap 128
//    forced 64 arch + 64 AGPR; ~80 v_accvgpr_read per step = the ~160cyc/wave-step gap.
//  - waves_per_eu(3,3): cap 170 regs/lane. Grid = 2731 waves / 1024 SIMDs = 2.67
//    waves/EU avg, so 3-wave occupancy is free; whole live set (~135) fits in arch VGPRs.
//  - log2(e) folded into pre-scaled weights; c kept in 2*log2e-scaled domain ->
//    activations are exp2/rcp with no range muls.
//  - Lanes 0-59: 3 rows x 20 units. Lanes 60-62: output lanes (whh row0=W2, v[0]=b2,
//    unscaled) -> their g0 IS out[t-1]. 640B dbuf LDS h-exchange, unroll x2,
//    single-wave workgroups (barrier free).

#define HID 20
#define ROWS_PER_WAVE 3
#define NTHREADS 64

#define L2E 1.4426950408889634f

__device__ __forceinline__ float exp2_hw(float v) { return __builtin_amdgcn_exp2f(v); }
__device__ __forceinline__ float rcp_hw(float v)  { return __builtin_amdgcn_rcpf(v); }

// gs = log2e * g          -> sigmoid(g)
__device__ __forceinline__ float sig_s(float gs) {
    return rcp_hw(1.0f + exp2_hw(-gs));
}
// gs2 = 2*log2e * g       -> 2*log2e * tanh(g)   (pre-scaled for the c update)
__device__ __forceinline__ float tanh_2Ls(float gs2) {
    return (2.0f * L2E) - (4.0f * L2E) * rcp_hw(1.0f + exp2_hw(gs2));
}
// cs = 2*log2e * c        -> tanh(c)
__device__ __forceinline__ float tanh_c(float cs) {
    return 1.0f - 2.0f * rcp_hw(1.0f + exp2_hw(cs));
}

__global__ __attribute__((amdgpu_flat_work_group_size(NTHREADS, NTHREADS),
                          amdgpu_waves_per_eu(3, 3)))
void lstm_wave(
        const float* __restrict__ x,     // [B, T]
        const float* __restrict__ W1,    // [20]
        const float* __restrict__ b1,    // [20]
        const float* __restrict__ W_ih,  // [80, 20]
        const float* __restrict__ W_hh,  // [80, 20]
        const float* __restrict__ b_ih,  // [80]
        const float* __restrict__ b_hh,  // [80]
        const float* __restrict__ W2,    // [20]
        const float* __restrict__ b2,    // [1]
        float* __restrict__ out,         // [B, T]
        const int B, const int T)
{
    const int lane = threadIdx.x;
    const int lrow = lane / HID;          // 0..3 (3 = special lanes 60-63)
    const int m    = lane % HID;          // 0..19
    const bool outlane = (lrow == 3) && (m < ROWS_PER_WAVE);   // lanes 60,61,62
    const int rslot = (lrow == 3) ? m : lrow;  // LDS row slot this lane READS
    const long rowbase = (long)blockIdx.x * ROWS_PER_WAVE;
    const long row = rowbase + ((lrow == 3) ? (long)((m < 3) ? m : 0) : (long)lrow);
    const long arow = (row < B) ? row : (B - 1);     // safe address for OOB/aux lanes
    const bool ovalid = outlane && (row < B);

    // [2 buffers][4 row slots (slot 3 = trash)][20 units]
    __shared__ __align__(16) float hbuf[2][ROWS_PER_WAVE + 1][HID];

    float whh[4][HID];   // gate lanes: scaled W_hh rows. out lanes: whh[0]=W2 (raw).
    float u[4], v[4];

    if (lrow < 3) {
        float w1r[HID], b1r[HID];
#pragma unroll
        for (int k = 0; k < HID; ++k) { w1r[k] = W1[k]; b1r[k] = b1[k]; }
#pragma unroll
        for (int g = 0; g < 4; ++g) {
            const int j = g * HID + m;            // torch gate order i,f,g,o
            const float s = (g == 2) ? (2.0f * L2E) : L2E;  // tanh gate gets 2*log2e
            float uu = 0.f, vv = 0.f;
#pragma unroll
            for (int k = 0; k < HID; ++k) {
                whh[g][k] = s * W_hh[j * HID + k];
                const float wi = W_ih[j * HID + k];
                uu += wi * w1r[k];
                vv += wi * b1r[k];
            }
            u[g] = s * uu;
            v[g] = s * (vv + b_ih[j] + b_hh[j]);
        }
    } else {
        // output lanes: gate-0 dot computes b2 + W2 @ h (unscaled)
#pragma unroll
        for (int g = 0; g < 4; ++g) { u[g] = 0.f; v[g] = 0.f; }
#pragma unroll
        for (int k = 0; k < HID; ++k) {
            whh[0][k] = W2[k];
            whh[1][k] = 0.f; whh[2][k] = 0.f; whh[3][k] = 0.f;
        }
        v[0] = b2[0];
    }

    // Opaque defs: prevent rematerialization of the weight loads into the loop.
#pragma unroll
    for (int g = 0; g < 4; ++g)
#pragma unroll
        for (int k = 0; k < HID; ++k)
            asm volatile("" : "+v"(whh[g][k]));

    float cs = 0.f;   // c in 2*log2e-scaled domain
    hbuf[0][lrow][m] = 0.f;
    hbuf[1][lrow][m] = 0.f;
    __syncthreads();

    const float* __restrict__ xrow = x   + arow * T;
    float* __restrict__       orow = out + arow * T;

    const float4* __restrict__ rd0 = (const float4*)&hbuf[0][rslot][0];
    const float4* __restrict__ rd1 = (const float4*)&hbuf[1][rslot][0];
    float* __restrict__ wr0 = &hbuf[1][lrow][m];   // body A writes buf1
    float* __restrict__ wr1 = &hbuf[0][lrow][m];   // body B writes buf0

    float xv_next = xrow[0];

    for (int t = 0; t < T; t += 2) {
        // ---- body A: h_t in buf0 -> h_{t+1} in buf1 ----
        {
            const float xv = xv_next;
            xv_next = xrow[t + 1];                 // t+1 <= T-1 always (T even)
            float g0 = v[0] + xv * u[0];
            float g1 = v[1] + xv * u[1];
            float g2 = v[2] + xv * u[2];
            float g3 = v[3] + xv * u[3];
#pragma unroll
            for (int q = 0; q < 5; ++q) {
                const float4 f = rd0[q];
                const float hk[4] = {f.x, f.y, f.z, f.w};
#pragma unroll
                for (int r = 0; r < 4; ++r) {
                    const int k = 4 * q + r;
                    g0 += whh[0][k] * hk[r];
                    g1 += whh[1][k] * hk[r];
                    g2 += whh[2][k] * hk[r];
                    g3 += whh[3][k] * hk[r];
                }
            }
            if (t > 0 && ovalid) orow[t - 1] = g0;   // out lanes: g0 = b2 + W2@h_t

            const float ig  = sig_s(g0);
            const float fg  = sig_s(g1);
            const float ggs = tanh_2Ls(g2);          // = 2L * tanh(g2)
            const float og  = sig_s(g3);
            cs = fg * cs + ig * ggs;                 // cs = 2L * c
            *wr0 = og * tanh_c(cs);
            __syncthreads();   // single-wave: lgkm drain only
        }
        // ---- body B: h_{t+1} in buf1 -> h_{t+2} in buf0 ----
        {
            const float xv = xv_next;
            const int tn = (t + 2 < T) ? (t + 2) : (T - 1);
            xv_next = xrow[tn];
            float g0 = v[0] + xv * u[0];
            float g1 = v[1] + xv * u[1];
            float g2 = v[2] + xv * u[2];
            float g3 = v[3] + xv * u[3];
#pragma unroll
            for (int q = 0; q < 5; ++q) {
                const float4 f = rd1[q];
                const float hk[4] = {f.x, f.y, f.z, f.w};
#pragma unroll
                for (int r = 0; r < 4; ++r) {
                    const int k = 4 * q + r;
                    g0 += whh[0][k] * hk[r];
                    g1 += whh[1][k] * hk[r];
                    g2 += whh[2][k] * hk[r];
                    g3 += whh[3][k] * hk[r];
                }
            }
            if (ovalid) orow[t] = g0;                // out lanes: g0 = b2 + W2@h_{t+1}

            const float ig  = sig_s(g0);
            const float fg  = sig_s(g1);
            const float ggs = tanh_2Ls(g2);
            const float og  = sig_s(g3);
            cs = fg * cs + ig * ggs;
            *wr1 = og * tanh_c(cs);
            __syncthreads();
        }
    }

    // epilogue: out[T-1] = b2 + W2 @ h_T ; h_T is in buf0 (T even)
    if (ovalid) {
        float o = v[0];
#pragma unroll
        for (int q = 0; q < 5; ++q) {
            const float4 f = rd0[q];
            o += whh[0][4*q+0] * f.x + whh[0][4*q+1] * f.y
               + whh[0][4*q+2] * f.z + whh[0][4*q+3] * f.w;
        }
        orow[T - 1] = o;
    }
}

extern "C" void kernel_launch(void* const* d_in, const int* in_sizes, int n_in,
                              void* d_out, int out_size, void* d_ws, size_t ws_size,
                              hipStream_t stream) {
    (void)n_in; (void)d_ws; (void)ws_size; (void)out_size;
    const float* x    = (const float*)d_in[0];
    const float* W1   = (const float*)d_in[1];
    const float* b1   = (const float*)d_in[2];
    const float* W_ih = (const float*)d_in[3];
    const float* W_hh = (const float*)d_in[4];
    const float* b_ih = (const float*)d_in[5];
    const float* b_hh = (const float*)d_in[6];
    const float* W2   = (const float*)d_in[7];
    const float* b2   = (const float*)d_in[8];
    float* out        = (float*)d_out;

    const int B = 8192;
    const int T = in_sizes[0] / B;  // 2048 (even)
    const int grid = (B + ROWS_PER_WAVE - 1) / ROWS_PER_WAVE;  // 2731 single-wave blocks

    lstm_wave<<<grid, NTHREADS, 0, stream>>>(x, W1, b1, W_ih, W_hh, b_ih, b_hh, W2, b2, out, B, T);
}

// Round 7
// 1180.212 us; speedup vs baseline: 2.2076x; 1.0395x over previous
//
#include <hip/hip_runtime.h>

// Net_4544075399853: x->20 linear, LSTMCell(20,20), 20->1 linear; B=8192, T=2048, fp32.
// R7: (a) preamble restructured so peak live-set stays < 128 (compute u,v BEFORE
//     loading whh; no w1r/b1r arrays held during the whh load) -> allocator has no
//     reason to AGPR-split; (b) dot products packed as float2 -> v_pk_fma_f32
//     (CDNA packed fp32, 2 FMA/inst full-rate): 40 pk_fma/step instead of 80 fmac.
//  - Lanes 0-59: 3 rows x 20 units; whh = 40 float2 (80 VGPRs) pinned via asm.
//  - Lanes 60-62: output lanes (whh row0=W2, v[0]=b2) -> their g0 IS out[t-1].
//  - exp2-domain activations (log2e pre-folded into weights; c kept 2*log2e-scaled).
//  - 640B dbuf LDS h-exchange, unroll x2, single-wave workgroups (barrier free).
//  - waves_per_eu(3,3): 168-reg cap; grid avg 2.67 waves/EU so 3 is free occupancy.

#define HID 20
#define ROWS_PER_WAVE 3
#define NTHREADS 64
#define L2E 1.4426950408889634f

typedef float v2f __attribute__((ext_vector_type(2)));

__device__ __forceinline__ float exp2_hw(float v) { return __builtin_amdgcn_exp2f(v); }
__device__ __forceinline__ float rcp_hw(float v)  { return __builtin_amdgcn_rcpf(v); }

// gs = log2e * g   -> sigmoid(g)
__device__ __forceinline__ float sig_s(float gs) {
    return rcp_hw(1.0f + exp2_hw(-gs));
}
// gs2 = 2*log2e*g  -> 2*log2e * tanh(g)  (pre-scaled for the c update)
__device__ __forceinline__ float tanh_2Ls(float gs2) {
    return (2.0f * L2E) - (4.0f * L2E) * rcp_hw(1.0f + exp2_hw(gs2));
}
// cs = 2*log2e*c   -> tanh(c)
__device__ __forceinline__ float tanh_c(float cs) {
    return 1.0f - 2.0f * rcp_hw(1.0f + exp2_hw(cs));
}

__global__ __attribute__((amdgpu_flat_work_group_size(NTHREADS, NTHREADS),
                          amdgpu_waves_per_eu(3, 3)))
void lstm_wave(
        const float* __restrict__ x,     // [B, T]
        const float* __restrict__ W1,    // [20]
        const float* __restrict__ b1,    // [20]
        const float* __restrict__ W_ih,  // [80, 20]
        const float* __restrict__ W_hh,  // [80, 20]
        const float* __restrict__ b_ih,  // [80]
        const float* __restrict__ b_hh,  // [80]
        const float* __restrict__ W2,    // [20]
        const float* __restrict__ b2,    // [1]
        float* __restrict__ out,         // [B, T]
        const int B, const int T)
{
    const int lane = threadIdx.x;
    const int lrow = lane / HID;          // 0..3 (3 = special lanes 60-63)
    const int m    = lane % HID;          // 0..19
    const bool outlane = (lrow == 3) && (m < ROWS_PER_WAVE);   // lanes 60,61,62
    const int rslot = (lrow == 3) ? m : lrow;  // LDS row slot this lane READS
    const long rowbase = (long)blockIdx.x * ROWS_PER_WAVE;
    const long row = rowbase + ((lrow == 3) ? (long)((m < 3) ? m : 0) : (long)lrow);
    const long arow = (row < B) ? row : (B - 1);     // safe address for OOB/aux lanes
    const bool ovalid = outlane && (row < B);

    // [2 buffers][4 row slots (slot 3 = trash)][20 units]
    __shared__ __align__(16) float hbuf[2][ROWS_PER_WAVE + 1][HID];

    // ---- phase 1: u, v (NO weight arrays live here; W1/b1 are uniform loads) ----
    float u[4], v[4];
    if (lrow < 3) {
#pragma unroll
        for (int g = 0; g < 4; ++g) {
            const int j = g * HID + m;            // torch gate order i,f,g,o
            const float s = (g == 2) ? (2.0f * L2E) : L2E;
            float uu = 0.f, vv = 0.f;
#pragma unroll
            for (int k = 0; k < HID; ++k) {
                const float wi = W_ih[j * HID + k];
                uu += wi * W1[k];
                vv += wi * b1[k];
            }
            u[g] = s * uu;
            v[g] = s * (vv + b_ih[j] + b_hh[j]);
        }
    } else {
#pragma unroll
        for (int g = 0; g < 4; ++g) { u[g] = 0.f; v[g] = 0.f; }
        v[0] = b2[0];
    }

    // ---- phase 2: whh as 40 float2 pairs (scaled), loaded with low live-set ----
    v2f whh2[4][HID / 2];
    if (lrow < 3) {
#pragma unroll
        for (int g = 0; g < 4; ++g) {
            const int j = g * HID + m;
            const float s = (g == 2) ? (2.0f * L2E) : L2E;
#pragma unroll
            for (int kk = 0; kk < HID / 2; ++kk) {
                v2f w;
                w.x = s * W_hh[j * HID + 2 * kk];
                w.y = s * W_hh[j * HID + 2 * kk + 1];
                whh2[g][kk] = w;
            }
        }
    } else {
#pragma unroll
        for (int kk = 0; kk < HID / 2; ++kk) {
            v2f w; w.x = W2[2 * kk]; w.y = W2[2 * kk + 1];
            whh2[0][kk] = w;
            whh2[1][kk] = (v2f)(0.f);
            whh2[2][kk] = (v2f)(0.f);
            whh2[3][kk] = (v2f)(0.f);
        }
    }

    // Opaque defs: prevent remat of the weight loads into the loop.
#pragma unroll
    for (int g = 0; g < 4; ++g)
#pragma unroll
        for (int kk = 0; kk < HID / 2; ++kk)
            asm volatile("" : "+v"(whh2[g][kk]));

    float cs = 0.f;   // c in 2*log2e-scaled domain
    hbuf[0][lrow][m] = 0.f;
    hbuf[1][lrow][m] = 0.f;
    __syncthreads();

    const float* __restrict__ xrow = x   + arow * T;
    float* __restrict__       orow = out + arow * T;

    const float4* __restrict__ rd0 = (const float4*)&hbuf[0][rslot][0];
    const float4* __restrict__ rd1 = (const float4*)&hbuf[1][rslot][0];
    float* __restrict__ wr0 = &hbuf[1][lrow][m];   // body A writes buf1
    float* __restrict__ wr1 = &hbuf[0][lrow][m];   // body B writes buf0

    float xv_next = xrow[0];

#define GATE_BODY(RD, WR, OUT_IDX_VALID, OUT_IDX)                               \
    {                                                                            \
        v2f a0, a1, a2, a3;                                                      \
        a0.x = v[0] + xv * u[0]; a0.y = 0.f;                                     \
        a1.x = v[1] + xv * u[1]; a1.y = 0.f;                                     \
        a2.x = v[2] + xv * u[2]; a2.y = 0.f;                                     \
        a3.x = v[3] + xv * u[3]; a3.y = 0.f;                                     \
        _Pragma("unroll")                                                        \
        for (int q = 0; q < 5; ++q) {                                            \
            const float4 f = RD[q];                                              \
            v2f hA; hA.x = f.x; hA.y = f.y;                                      \
            v2f hB; hB.x = f.z; hB.y = f.w;                                      \
            a0 = __builtin_elementwise_fma(whh2[0][2*q],   hA, a0);              \
            a1 = __builtin_elementwise_fma(whh2[1][2*q],   hA, a1);              \
            a2 = __builtin_elementwise_fma(whh2[2][2*q],   hA, a2);              \
            a3 = __builtin_elementwise_fma(whh2[3][2*q],   hA, a3);              \
            a0 = __builtin_elementwise_fma(whh2[0][2*q+1], hB, a0);              \
            a1 = __builtin_elementwise_fma(whh2[1][2*q+1], hB, a1);              \
            a2 = __builtin_elementwise_fma(whh2[2][2*q+1], hB, a2);              \
            a3 = __builtin_elementwise_fma(whh2[3][2*q+1], hB, a3);              \
        }                                                                        \
        const float g0 = a0.x + a0.y;                                            \
        const float g1 = a1.x + a1.y;                                            \
        const float g2 = a2.x + a2.y;                                            \
        const float g3 = a3.x + a3.y;                                            \
        if ((OUT_IDX_VALID) && ovalid) orow[OUT_IDX] = g0;                       \
        const float ig  = sig_s(g0);                                             \
        const float fg  = sig_s(g1);                                             \
        const float ggs = tanh_2Ls(g2);                                          \
        const float og  = sig_s(g3);                                             \
        cs = fg * cs + ig * ggs;                                                 \
        *(WR) = og * tanh_c(cs);                                                 \
        __syncthreads();                                                         \
    }

    for (int t = 0; t < T; t += 2) {
        // ---- body A: h_t in buf0 -> h_{t+1} in buf1 ----
        {
            const float xv = xv_next;
            xv_next = xrow[t + 1];                 // t+1 <= T-1 always (T even)
            GATE_BODY(rd0, wr0, t > 0, t - 1)
        }
        // ---- body B: h_{t+1} in buf1 -> h_{t+2} in buf0 ----
        {
            const float xv = xv_next;
            const int tn = (t + 2 < T) ? (t + 2) : (T - 1);   // uniform (SALU) clamp
            xv_next = xrow[tn];
            GATE_BODY(rd1, wr1, true, t)
        }
    }

    // epilogue: out[T-1] = b2 + W2 @ h_T ; h_T is in buf0 (T even)
    if (ovalid) {
        float o = v[0];
#pragma unroll
        for (int q = 0; q < 5; ++q) {
            const float4 f = rd0[q];
            o += whh2[0][2*q].x   * f.x + whh2[0][2*q].y   * f.y
               + whh2[0][2*q+1].x * f.z + whh2[0][2*q+1].y * f.w;
        }
        orow[T - 1] = o;
    }
#undef GATE_BODY
}

extern "C" void kernel_launch(void* const* d_in, const int* in_sizes, int n_in,
                              void* d_out, int out_size, void* d_ws, size_t ws_size,
                              hipStream_t stream) {
    (void)n_in; (void)d_ws; (void)ws_size; (void)out_size;
    const float* x    = (const float*)d_in[0];
    const float* W1   = (const float*)d_in[1];
    const float* b1   = (const float*)d_in[2];
    const float* W_ih = (const float*)d_in[3];
    const float* W_hh = (const float*)d_in[4];
    const float* b_ih = (const float*)d_in[5];
    const float* b_hh = (const float*)d_in[6];
    const float* W2   = (const float*)d_in[7];
    const float* b2   = (const float*)d_in[8];
    float* out        = (float*)d_out;

    const int B = 8192;
    const int T = in_sizes[0] / B;  // 2048 (even)
    const int grid = (B + ROWS_PER_WAVE - 1) / ROWS_PER_WAVE;  // 2731 single-wave blocks

    lstm_wave<<<grid, NTHREADS, 0, stream>>>(x, W1, b1, W_ih, W_hh, b_ih, b_hh, W2, b2, out, B, T);
}